// Round 6
// baseline (3524.553 us; speedup 1.0000x reference)
//
#include <hip/hip_runtime.h>
#include <math.h>

#define NB   262144   // batch (tokens)
#define DD   512      // d_routing
#define NG   4        // groups
#define NGS  4        // group size
#define NOUT 20       // 4 group logits + 16 in-group logits

#define TPB        256          // threads per block
#define TOKS       256          // tokens per block (1 per thread)
#define CH         32           // floats of D per staged chunk (= one 128B line/token)
#define NCHUNK     (DD / CH)    // 16
#define GRP_FLOATS 260          // 8 tokens * 32 floats + 4 pad floats
#define NGRP       (TOKS / 8)   // 32 staging groups per chunk
#define WROWS      24           // 20 weight rows padded to 24 (3 full instructions)

typedef float f32x4 __attribute__((ext_vector_type(4)));

// global_load_lds: LDS dest is wave-uniform base + lane*16B (linear);
// global src is per-lane.
#define GLOAD_LDS16(gsrc, ldst)                                                \
    __builtin_amdgcn_global_load_lds(                                          \
        (const __attribute__((address_space(1))) unsigned int*)(gsrc),         \
        (__attribute__((address_space(3))) unsigned int*)(ldst), 16, 0, 0)

// Double-buffered prefetch pipeline (T3 "minimum 2-phase" template):
//   prologue: stage(chunk0, buf0); barrier
//   loop ch:  stage(ch+1, buf^1)  -> loads in flight during compute
//             compute(ch, buf)
//             one vmcnt(0)+barrier per chunk (__syncthreads)
// Memory streams continuously instead of idling during compute (the round-5
// limiter: stage->drain->compute serialized each chunk at ~50% HBM duty).
__global__ __launch_bounds__(TPB, 2) void router_k(
    const float* __restrict__ x,        // [NB, DD]
    const float* __restrict__ group_w,  // [NG, DD]
    const float* __restrict__ group_b,  // [NG]
    const float* __restrict__ in_w,     // [NG*NGS, DD]
    const float* __restrict__ in_b,     // [NG, NGS]
    const int*   __restrict__ experts,  // [NG, NGS]
    float*       __restrict__ out)      // [2*NB*2]: indices then weights, fp32
{
    __shared__ float xbuf[2][NGRP * GRP_FLOATS];  // 2 x 33280 B
    __shared__ float wbuf[2][WROWS * CH];         // 2 x  3072 B

    const int tid  = threadIdx.x;
    const int wid  = tid >> 6;
    const int lane = tid & 63;
    const int tok0 = blockIdx.x * TOKS;

    const int lrow = lane >> 3;        // token-in-group for staging
    const int lcol = (lane & 7) * 4;   // float offset within 128B line

    // This thread's token slot inside a buffer.
    const int xoff = (tid >> 3) * GRP_FLOATS + (tid & 7) * CH;

    float acc[NOUT];
#pragma unroll
    for (int o = 0; o < NOUT; ++o) acc[o] = 0.f;

    // ---- stage one chunk into buffer `buf` ----
    auto stage = [&](int ch, int buf) {
        const int dd = ch * CH;
#pragma unroll
        for (int kk = 0; kk < 8; ++kk) {
            const int k = wid * 8 + kk;
            const float* src =
                x + ((size_t)(tok0 + k * 8 + lrow)) * DD + dd + lcol;
            GLOAD_LDS16(src, &xbuf[buf][k * GRP_FLOATS]);
        }
        if (wid == 0) {
#pragma unroll
            for (int m = 0; m < 3; ++m) {
                int R = m * 8 + lrow;
                if (R > 19) R = 19;  // dup row 19 into pad rows 20..23
                const float* wr = (R < NG) ? (group_w + R * DD)
                                           : (in_w + (R - NG) * DD);
                GLOAD_LDS16(wr + dd + lcol, &wbuf[buf][m * 8 * CH]);
            }
        }
    };

    stage(0, 0);
    __syncthreads();  // vmcnt(0) drain + barrier: buf0 ready

    for (int ch = 0; ch < NCHUNK; ++ch) {
        const int cur = ch & 1;

        // Prefetch next chunk first -> its HBM transfer overlaps this compute.
        if (ch + 1 < NCHUNK) stage(ch + 1, cur ^ 1);

        const float* xb = &xbuf[cur][xoff];
        const float* wb = &wbuf[cur][0];

#pragma unroll
        for (int g = 0; g < 8; ++g) {
            const f32x4 xv = *reinterpret_cast<const f32x4*>(xb + g * 4);
#pragma unroll
            for (int o = 0; o < NOUT; ++o) {
                const f32x4 w =
                    *reinterpret_cast<const f32x4*>(wb + o * CH + g * 4);
                float a = acc[o];
                a = fmaf(xv.x, w.x, a);
                a = fmaf(xv.y, w.y, a);
                a = fmaf(xv.z, w.z, a);
                a = fmaf(xv.w, w.w, a);
                acc[o] = a;
            }
        }

        // One drain+barrier per chunk: ensures (a) next buffer's loads landed,
        // (b) everyone is done reading `cur` before ch+2 overwrites it.
        if (ch + 1 < NCHUNK) __syncthreads();
    }

    // ---- epilogue (one token per thread) ----
    const int t = tok0 + tid;

    // group argmax (first-max tie-break, matches jnp.argmax)
    float gl[NG];
#pragma unroll
    for (int g = 0; g < NG; ++g) gl[g] = acc[g] + group_b[g];
    int bg = 0;
    float bv = gl[0];
#pragma unroll
    for (int g = 1; g < NG; ++g)
        if (gl[g] > bv) { bv = gl[g]; bg = g; }

    // select chosen group's in-logits without runtime indexing
    float il[NGS];
#pragma unroll
    for (int k = 0; k < NGS; ++k) il[k] = 0.f;
#pragma unroll
    for (int g = 0; g < NG; ++g) {
        const bool sel = (g == bg);
#pragma unroll
        for (int k = 0; k < NGS; ++k)
            il[k] = sel ? acc[NG + g * NGS + k] : il[k];
    }
#pragma unroll
    for (int k = 0; k < NGS; ++k) il[k] += in_b[bg * NGS + k];

    // softmax (fp32, subtract-max)
    float m = fmaxf(fmaxf(il[0], il[1]), fmaxf(il[2], il[3]));
    float p[NGS];
    float s = 0.f;
#pragma unroll
    for (int k = 0; k < NGS; ++k) { p[k] = expf(il[k] - m); s += p[k]; }
    const float inv = 1.0f / s;
#pragma unroll
    for (int k = 0; k < NGS; ++k) p[k] *= inv;

    // top-2 (descending, lower-index-on-tie, matches lax.top_k)
    int i1 = 0;
    float v1 = p[0];
#pragma unroll
    for (int k = 1; k < NGS; ++k)
        if (p[k] > v1) { v1 = p[k]; i1 = k; }
    int i2 = -1;
    float v2 = -3.0e38f;
#pragma unroll
    for (int k = 0; k < NGS; ++k)
        if (k != i1 && p[k] > v2) { v2 = p[k]; i2 = k; }

    const int id1 = experts[bg * NGS + i1];
    const int id2 = experts[bg * NGS + i2];

    float2* outi = reinterpret_cast<float2*>(out);
    float2* outw = reinterpret_cast<float2*>(out + (size_t)NB * 2);
    outi[t] = make_float2((float)id1, (float)id2);
    outw[t] = make_float2(v1, v2);
}

extern "C" void kernel_launch(void* const* d_in, const int* in_sizes, int n_in,
                              void* d_out, int out_size, void* d_ws, size_t ws_size,
                              hipStream_t stream) {
    const float* x  = (const float*)d_in[0];
    const float* gw = (const float*)d_in[1];
    const float* gb = (const float*)d_in[2];
    const float* iw = (const float*)d_in[3];
    const float* ib = (const float*)d_in[4];
    const int*   et = (const int*)d_in[5];
    float* out = (float*)d_out;

    router_k<<<dim3(NB / TOKS), dim3(TPB), 0, stream>>>(x, gw, gb, iw, ib, et, out);
}

// Round 7
// 259.503 us; speedup vs baseline: 13.5820x; 13.5820x over previous
//
#include <hip/hip_runtime.h>
#include <math.h>

#define NB     262144   // batch (tokens)
#define DD     512      // d_routing
#define NG     4        // groups
#define NGS    4        // group size
#define NOUT   20       // 4 group logits + 16 in-group logits

#define TPB    128      // threads per block (2 waves)
#define T      4        // tokens per thread -> w-broadcast LDS cost /4
#define TOKS   512      // tokens per block
#define CH     16       // floats of D per chunk per token (64 B)
#define NCHUNK 32       // DD / CH
#define GRP    260      // 16 tokens * 16 floats + 4 pad floats (group stride)
#define NXG    32       // staging groups per chunk (TOKS/16)

typedef float f32x4 __attribute__((ext_vector_type(4)));

// LDS dest must be wave-uniform AND compile-time-selected (round-6 lesson:
// a runtime-indexed buffer select defeats uniformity analysis -> 20x cliff).
#define GLOAD_LDS16(gsrc, ldst)                                                \
    __builtin_amdgcn_global_load_lds(                                          \
        (const __attribute__((address_space(1))) unsigned int*)(gsrc),         \
        (__attribute__((address_space(3))) unsigned int*)(ldst), 16, 0, 0)

// Stage x chunk `ch` into static buffer XB. 16 instr/wave; each = 16 tokens x
// 64B, LDS dest linear 1KB. The global source is PRE-SWIZZLED (slot rotation
// slot=(g+((t&15)>>2))&3) so the compute-side reads are bank-conflict-free.
#define STAGE_X(ch, XB) do {                                                   \
    const int dd_ = (ch) * CH;                                                 \
    _Pragma("unroll")                                                          \
    for (int kk = 0; kk < 16; ++kk) {                                          \
        const int k_ = wid * 16 + kk;                                          \
        const float* src_ =                                                    \
            x + (size_t)(tok0 + k_ * 16 + sj) * DD + dd_ + scol;               \
        GLOAD_LDS16(src_, &XB[k_ * GRP]);                                      \
    }                                                                          \
} while (0)

// Stage w chunk: 20 rows x 64B; 1 instr per wave (rows wid*16.., clamp-dup).
#define STAGE_W(ch, WB) do {                                                   \
    const int dd_ = (ch) * CH;                                                 \
    GLOAD_LDS16(wrow + dd_ + wcol, &WB[wid * 256]);                            \
} while (0)

#define COMPUTE(XB, WB) do {                                                   \
    _Pragma("unroll")                                                          \
    for (int g = 0; g < 4; ++g) {                                              \
        const int slot_ = ((g + aperm) & 3) * 4;                               \
        const f32x4 xv0 = *(const f32x4*)&XB[xo0 + slot_];                     \
        const f32x4 xv1 = *(const f32x4*)&XB[xo1 + slot_];                     \
        const f32x4 xv2 = *(const f32x4*)&XB[xo2 + slot_];                     \
        const f32x4 xv3 = *(const f32x4*)&XB[xo3 + slot_];                     \
        _Pragma("unroll")                                                      \
        for (int o = 0; o < NOUT; ++o) {                                       \
            const f32x4 w = *(const f32x4*)&WB[o * 16 + g * 4];                \
            acc0[o] = fmaf(xv0.x, w.x, acc0[o]);                               \
            acc0[o] = fmaf(xv0.y, w.y, acc0[o]);                               \
            acc0[o] = fmaf(xv0.z, w.z, acc0[o]);                               \
            acc0[o] = fmaf(xv0.w, w.w, acc0[o]);                               \
            acc1[o] = fmaf(xv1.x, w.x, acc1[o]);                               \
            acc1[o] = fmaf(xv1.y, w.y, acc1[o]);                               \
            acc1[o] = fmaf(xv1.z, w.z, acc1[o]);                               \
            acc1[o] = fmaf(xv1.w, w.w, acc1[o]);                               \
            acc2[o] = fmaf(xv2.x, w.x, acc2[o]);                               \
            acc2[o] = fmaf(xv2.y, w.y, acc2[o]);                               \
            acc2[o] = fmaf(xv2.z, w.z, acc2[o]);                               \
            acc2[o] = fmaf(xv2.w, w.w, acc2[o]);                               \
            acc3[o] = fmaf(xv3.x, w.x, acc3[o]);                               \
            acc3[o] = fmaf(xv3.y, w.y, acc3[o]);                               \
            acc3[o] = fmaf(xv3.z, w.z, acc3[o]);                               \
            acc3[o] = fmaf(xv3.w, w.w, acc3[o]);                               \
        }                                                                      \
    }                                                                          \
} while (0)

__global__ __launch_bounds__(TPB, 1) void router_k(
    const float* __restrict__ x,        // [NB, DD]
    const float* __restrict__ group_w,  // [NG, DD]
    const float* __restrict__ group_b,  // [NG]
    const float* __restrict__ in_w,     // [NG*NGS, DD]
    const float* __restrict__ in_b,     // [NG, NGS]
    const int*   __restrict__ experts,  // [NG, NGS]
    float*       __restrict__ out)      // [2*NB*2]: indices then weights, fp32
{
    // Static double buffers: compile-time symbol per call site, never
    // runtime-selected (round-6 pathology guard).
    __shared__ float xbA[NXG * GRP];  // 33280 B
    __shared__ float xbB[NXG * GRP];  // 33280 B
    __shared__ float wbA[512];        //  2048 B (32 rows x 16 floats)
    __shared__ float wbB[512];        //  2048 B

    const int tid  = threadIdx.x;
    const int wid  = tid >> 6;   // 0..1
    const int lane = tid & 63;
    const int tok0 = blockIdx.x * TOKS;

    // --- staging-side constants (write is linear; source is pre-swizzled) ---
    const int sj   = lane >> 2;                          // token-in-group
    const int scol = ((((lane & 3) - (lane >> 4)) & 3)) * 4;  // swizzled granule

    int wR = wid * 16 + (lane >> 2);
    if (wR > 19) wR = 19;                                // clamp-dup pad rows
    const float* wrow = (wR < NG) ? (group_w + (size_t)wR * DD)
                                  : (in_w + (size_t)(wR - NG) * DD);
    const int wcol = (lane & 3) * 4;

    // --- compute-side constants ---
    const int aperm = (tid >> 2) & 3;                    // = (token&15)>>2
    const int xo0 = (((tid >> 4) + 0)  * GRP) + (tid & 15) * 16;
    const int xo1 = (((tid >> 4) + 8)  * GRP) + (tid & 15) * 16;
    const int xo2 = (((tid >> 4) + 16) * GRP) + (tid & 15) * 16;
    const int xo3 = (((tid >> 4) + 24) * GRP) + (tid & 15) * 16;

    float acc0[NOUT], acc1[NOUT], acc2[NOUT], acc3[NOUT];
#pragma unroll
    for (int o = 0; o < NOUT; ++o) {
        acc0[o] = 0.f; acc1[o] = 0.f; acc2[o] = 0.f; acc3[o] = 0.f;
    }

    STAGE_X(0, xbA);
    STAGE_W(0, wbA);
    __syncthreads();   // drain: buf A ready

#pragma unroll 1
    for (int ch = 0; ch < NCHUNK; ch += 2) {
        // Prefetch ch+1 into B while computing A (loads in flight past compute)
        STAGE_X(ch + 1, xbB);
        STAGE_W(ch + 1, wbB);
        COMPUTE(xbA, wbA);
        __syncthreads();   // B landed; everyone done reading A

        if (ch + 2 < NCHUNK) { STAGE_X(ch + 2, xbA); STAGE_W(ch + 2, wbA); }
        COMPUTE(xbB, wbB);
        if (ch + 2 < NCHUNK) __syncthreads();  // A landed; done reading B
    }

    // ---- epilogue: 4 tokens per thread ----
    float2* outi = reinterpret_cast<float2*>(out);
    float2* outw = reinterpret_cast<float2*>(out + (size_t)NB * 2);

#pragma unroll
    for (int tk = 0; tk < T; ++tk) {
        const float* acc = (tk == 0) ? acc0 : (tk == 1) ? acc1
                         : (tk == 2) ? acc2 : acc3;     // unroll-constant select
        const int t = tok0 + tid + tk * TPB;

        // group argmax (first-max tie-break, matches jnp.argmax)
        float gl[NG];
#pragma unroll
        for (int g = 0; g < NG; ++g) gl[g] = acc[g] + group_b[g];
        int bg = 0;
        float bv = gl[0];
#pragma unroll
        for (int g = 1; g < NG; ++g)
            if (gl[g] > bv) { bv = gl[g]; bg = g; }

        // select chosen group's in-logits without runtime indexing
        float il[NGS];
#pragma unroll
        for (int k = 0; k < NGS; ++k) il[k] = 0.f;
#pragma unroll
        for (int g = 0; g < NG; ++g) {
            const bool sel = (g == bg);
#pragma unroll
            for (int k = 0; k < NGS; ++k)
                il[k] = sel ? acc[NG + g * NGS + k] : il[k];
        }
#pragma unroll
        for (int k = 0; k < NGS; ++k) il[k] += in_b[bg * NGS + k];

        // softmax (fp32, subtract-max)
        float m = fmaxf(fmaxf(il[0], il[1]), fmaxf(il[2], il[3]));
        float p[NGS];
        float s = 0.f;
#pragma unroll
        for (int k = 0; k < NGS; ++k) { p[k] = expf(il[k] - m); s += p[k]; }
        const float inv = 1.0f / s;
#pragma unroll
        for (int k = 0; k < NGS; ++k) p[k] *= inv;

        // top-2 (descending, lower-index-on-tie, matches lax.top_k)
        int i1 = 0;
        float v1 = p[0];
#pragma unroll
        for (int k = 1; k < NGS; ++k)
            if (p[k] > v1) { v1 = p[k]; i1 = k; }
        int i2 = -1;
        float v2 = -3.0e38f;
#pragma unroll
        for (int k = 0; k < NGS; ++k)
            if (k != i1 && p[k] > v2) { v2 = p[k]; i2 = k; }

        const int id1 = experts[bg * NGS + i1];
        const int id2 = experts[bg * NGS + i2];

        outi[t] = make_float2((float)id1, (float)id2);
        outw[t] = make_float2(v1, v2);
    }
}

extern "C" void kernel_launch(void* const* d_in, const int* in_sizes, int n_in,
                              void* d_out, int out_size, void* d_ws, size_t ws_size,
                              hipStream_t stream) {
    const float* x  = (const float*)d_in[0];
    const float* gw = (const float*)d_in[1];
    const float* gb = (const float*)d_in[2];
    const float* iw = (const float*)d_in[3];
    const float* ib = (const float*)d_in[4];
    const int*   et = (const int*)d_in[5];
    float* out = (float*)d_out;

    router_k<<<dim3(NB / TOKS), dim3(TPB), 0, stream>>>(x, gw, gb, iw, ib, et, out);
}